// Round 12
// baseline (147.395 us; speedup 1.0000x reference)
//
#include <hip/hip_runtime.h>
#include <stdint.h>

#define BB 4
#define CC 256
#define NN 4096
#define GG 8

typedef unsigned short u16;
typedef __attribute__((ext_vector_type(4))) float f32x4;
typedef __attribute__((ext_vector_type(16))) float f32x16;
typedef __attribute__((ext_vector_type(8))) short s16x8;
typedef __attribute__((ext_vector_type(4))) u16 u16x4;
typedef __attribute__((ext_vector_type(8))) u16 u16x8;

#define QSCALE 0.0901684857f  /* log2(e)/16 folded into wq/bq */

__device__ __forceinline__ u16 f2bf(float f) {
  union { float f; uint32_t u; } v; v.f = f;
  return (u16)((v.u + 0x7FFFu + ((v.u >> 16) & 1u)) >> 16);
}
__device__ __forceinline__ float bf2f(uint32_t u) {
  union { uint32_t u; float f; } v; v.u = u << 16;
  return v.f;
}

__device__ __forceinline__ void async16(const void* g, void* l) {
  __builtin_amdgcn_global_load_lds(
      (const __attribute__((address_space(1))) void*)g,
      (__attribute__((address_space(3))) void*)l, 16, 0, 0);
}

// ======== fused weight-cvt (256 blocks) + GN partial sums (512 blocks) ========
__global__ __launch_bounds__(256) void prep_kernel(
    const float* __restrict__ wq, const float* __restrict__ wk,
    const float* __restrict__ wv, const float* __restrict__ wp,
    u16* __restrict__ dst, const float* __restrict__ x,
    float* __restrict__ part) {
  const int bid = blockIdx.x;
  if (bid < 256) {
    const int mat = bid >> 6;
    const float* src = (mat == 0) ? wq : (mat == 1) ? wk : (mat == 2) ? wv : wp;
    const float sc = (mat == 0) ? QSCALE : 1.0f;
    int i = (bid & 63) * 256 + threadIdx.x;
    f32x4 v = ((const f32x4*)src)[i];
    u16x4 o;
    o[0] = f2bf(v[0]*sc); o[1] = f2bf(v[1]*sc);
    o[2] = f2bf(v[2]*sc); o[3] = f2bf(v[3]*sc);
    ((u16x4*)(dst + (size_t)mat * 65536))[i] = o;
    return;
  }
  const int id = bid - 256;
  const int bg = id >> 4, seg = id & 15;  // 32 x 16
  const f32x4* xp = (const f32x4*)(x + (size_t)bg * 131072 + seg * 8192);
  float s = 0.f, ss = 0.f;
  for (int i = threadIdx.x; i < 2048; i += 256) {
    f32x4 v = xp[i];
    s += v[0] + v[1] + v[2] + v[3];
    ss += v[0]*v[0] + v[1]*v[1] + v[2]*v[2] + v[3]*v[3];
  }
  for (int d = 1; d < 64; d <<= 1) {
    s += __shfl_xor(s, d, 64);
    ss += __shfl_xor(ss, d, 64);
  }
  __shared__ float red[8];
  int w = threadIdx.x >> 6, lane = threadIdx.x & 63;
  if (lane == 0) { red[w*2] = s; red[w*2+1] = ss; }
  __syncthreads();
  if (threadIdx.x == 0) {
    part[(bg*16 + seg)*2]     = red[0]+red[2]+red[4]+red[6];
    part[(bg*16 + seg)*2 + 1] = red[1]+red[3]+red[5]+red[7];
  }
}

// ======== fused GN-apply + QKV GEMM ========
__global__ __launch_bounds__(512) void gnqkv_kernel(
    const float* __restrict__ x, const float* __restrict__ part,
    const float* __restrict__ gamma, const float* __restrict__ beta,
    const u16* __restrict__ wbf,
    const float* __restrict__ bq, const float* __restrict__ bk,
    const float* __restrict__ bv,
    u16* __restrict__ Qtm, u16* __restrict__ Ktm, u16* __restrict__ Vcm) {
  __shared__ float gstat[16];
  __shared__ char t1[32768];  // [256 c][64 n] bf16, XOR-swizzled
  __shared__ char t2[32768];  // [64 n][256 c] bf16, row-swizzled for B-frags
  const int b = blockIdx.y, n0 = blockIdx.x * 64, t = threadIdx.x;
  if (t < 8) {
    float S = 0.f, SS = 0.f;
    for (int seg = 0; seg < 16; ++seg) {
      S  += part[((b*8 + t)*16 + seg)*2];
      SS += part[((b*8 + t)*16 + seg)*2 + 1];
    }
    float mean = S * (1.0f/131072.0f);
    float var = SS * (1.0f/131072.0f) - mean*mean;
    gstat[t*2] = mean;
    gstat[t*2+1] = rsqrtf(var + 1e-5f);
  }
  __syncthreads();
  for (int p = 0; p < 8; ++p) {
    int c = p*32 + (t >> 4);
    int n4 = (t & 15) * 4;
    f32x4 v = *(const f32x4*)(x + ((size_t)b*CC + c)*NN + n0 + n4);
    float mean = gstat[(c>>5)*2], rstd = gstat[(c>>5)*2+1];
    float ga = gamma[c] * rstd;
    float be = beta[c] - mean * ga;
    u16x4 o;
    o[0]=f2bf(v[0]*ga+be); o[1]=f2bf(v[1]*ga+be);
    o[2]=f2bf(v[2]*ga+be); o[3]=f2bf(v[3]*ga+be);
    int swz = (((c & 7) ^ ((c >> 3) & 7)) << 4);
    *(u16x4*)(t1 + c*128 + ((n4*2) ^ swz)) = o;
  }
  __syncthreads();
  for (int p = 0; p < 4; ++p) {
    int n = p*16 + (t >> 5);
    int c0 = (t & 31) * 8;
    u16x8 o;
#pragma unroll
    for (int j = 0; j < 8; ++j) {
      int c = c0 + j;
      int swz = (((c & 7) ^ ((c >> 3) & 7)) << 4);
      o[j] = *(const u16*)(t1 + c*128 + ((n*2) ^ swz));
    }
    *(u16x8*)(t2 + n*512 + ((c0*2) ^ ((n & 7) << 4))) = o;
  }
  __syncthreads();
  const int lane = t & 63, w = t >> 6;
  const int wn = w >> 2, wo = w & 3;
  const int hi = lane >> 4, lo = lane & 15;
#pragma unroll
  for (int mat = 0; mat < 3; ++mat) {
    const u16* wm = wbf + mat*65536;
    f32x4 acc[2][4] = {};
    for (int kc = 0; kc < 8; ++kc) {
      s16x8 xf[2];
#pragma unroll
      for (int nf = 0; nf < 2; ++nf) {
        int n = wn*32 + nf*16 + lo;
        xf[nf] = *(const s16x8*)(t2 + n*512 + ((kc*64 + hi*16) ^ ((n & 7) << 4)));
      }
#pragma unroll
      for (int of = 0; of < 4; ++of) {
        int o = wo*64 + of*16 + lo;
        s16x8 wf = *(const s16x8*)(wm + (size_t)o*256 + kc*32 + hi*8);
        if (mat < 2) {
          acc[0][of] = __builtin_amdgcn_mfma_f32_16x16x32_bf16(xf[0], wf, acc[0][of], 0, 0, 0);
          acc[1][of] = __builtin_amdgcn_mfma_f32_16x16x32_bf16(xf[1], wf, acc[1][of], 0, 0, 0);
        } else {
          acc[0][of] = __builtin_amdgcn_mfma_f32_16x16x32_bf16(wf, xf[0], acc[0][of], 0, 0, 0);
          acc[1][of] = __builtin_amdgcn_mfma_f32_16x16x32_bf16(wf, xf[1], acc[1][of], 0, 0, 0);
        }
      }
    }
    if (mat < 2) {
      u16* Y = (mat == 0) ? Qtm : Ktm;
      const float* bias = (mat == 0) ? bq : bk;
      const float bsc = (mat == 0) ? QSCALE : 1.0f;
#pragma unroll
      for (int nf = 0; nf < 2; ++nf)
#pragma unroll
        for (int of = 0; of < 4; ++of) {
          int oc = wo*64 + of*16 + lo;
          float bvv = bias[oc] * bsc;
#pragma unroll
          for (int r = 0; r < 4; ++r) {
            int n = n0 + wn*32 + nf*16 + hi*4 + r;
            Y[((size_t)b*NN + n)*CC + oc] = f2bf(acc[nf][of][r] + bvv);
          }
        }
    } else {
#pragma unroll
      for (int nf = 0; nf < 2; ++nf)
#pragma unroll
        for (int of = 0; of < 4; ++of)
#pragma unroll
          for (int r = 0; r < 4; ++r) {
            int oc = wo*64 + of*16 + hi*4 + r;
            int n = n0 + wn*32 + nf*16 + lo;
            Vcm[((size_t)b*CC + oc)*NN + n] = f2bf(acc[nf][of][r] + bv[oc]);
          }
    }
  }
}

// ======== flash v12: V 3-buffer ring, narrowed barrier2, earliest stage issue ==
// Window it: [vmcnt+bar] stageV(it) ; S(it) MFMA ∥ softmax(it-1) ; [bar]
//            stageK(it+2) ; PV(it-1).
// K dbuf 32KB + V ring 48KB = 80KB/block, 2 blocks/CU = 160KB (exact fit).
__global__ __launch_bounds__(256, 2) void flash_kernel(
    const u16* __restrict__ Q, const u16* __restrict__ K,
    const u16* __restrict__ V, uint32_t* __restrict__ Op32,
    float* __restrict__ Lpart) {
  extern __shared__ char smem[];
  char* kl = smem;            // 2 x 16KB: [32 cslot][32 m][16B]
  char* vl = smem + 32768;    // 3 x 16KB: [4 mslot][256 c][16B]
  const int bid = blockIdx.x;
  const int b    = bid & 3;
  const int part = ((bid >> 2) & 1) | (((bid >> 8) & 1) << 1);
  const int qb   = (bid >> 3) & 31;
  const int tid = threadIdx.x;
  const int lane = tid & 63;
  const int w = tid >> 6;
  const int cl = lane & 31;
  const int h = lane >> 5;
  const int q = qb*128 + w*32 + cl;

  s16x8 qreg[16];
  {
    const u16* qp = Q + ((size_t)b*NN + q)*CC + h*8;
#pragma unroll
    for (int kc = 0; kc < 16; ++kc) qreg[kc] = *(const s16x8*)(qp + kc*16);
  }
  f32x16 oacc[8];
#pragma unroll
  for (int i = 0; i < 8; ++i) oacc[i] = (f32x16)0.f;
  float Lp = 0.f;

  const char* kbase = (const char*)(K + (size_t)b*NN*CC);
  const char* vbase = (const char*)(V + (size_t)b*CC*NN);
  const int mbase = part*1024;

  auto stageK = [&](int buf, int m0) {
#pragma unroll
    for (int p = 0; p < 4; ++p)   // K: [cslot][m][16B]
      async16(kbase + (size_t)(m0 + (tid & 31))*512 + ((tid >> 5) + p*8)*16,
              kl + buf*16384 + p*4096 + tid*16);
  };
  auto stageV = [&](int slot, int m0) {
#pragma unroll
    for (int p = 0; p < 4; ++p)   // V: [mslot][c][16B]
      async16(vbase + (size_t)tid*8192 + (size_t)m0*2 + p*16,
              vl + slot*16384 + p*4096 + tid*16);
  };

  stageK(0, mbase);
  stageK(1, mbase + 32);

  f32x16 s_prev;                 // S(it-1), carried across the barrier
  s16x8 pf[2];                   // P(it-1) frags, built this window

  for (int it = 0; it < 32; ++it) {
    const int cur = it & 1;
    const int vsW = it % 3;            // V(it) write slot
    const int vsR = (it + 2) % 3;      // V(it-1) read slot
    if (it == 31) asm volatile("s_waitcnt vmcnt(0)" ::: "memory");
    else          asm volatile("s_waitcnt vmcnt(4)" ::: "memory");
    __builtin_amdgcn_s_barrier();
    asm volatile("" ::: "memory");

    stageV(vsW, mbase + it*32);        // earliest possible issue; full-window flight

    // S(it) MFMA chain ∥ softmax(it-1) VALU (proven v11 overlap)
    f32x16 s0 = (f32x16)0.f;
    __builtin_amdgcn_s_setprio(1);
#pragma unroll
    for (int kc = 0; kc < 16; ++kc) {
      s16x8 kf = *(const s16x8*)(kl + cur*16384 + (kc*2 + h)*512 + cl*16);
      s0 = __builtin_amdgcn_mfma_f32_32x32x16_bf16(kf, qreg[kc], s0, 0, 0, 0);
    }
    if (it > 0) {
#pragma unroll
      for (int half = 0; half < 2; ++half) {
        float pe[8];
#pragma unroll
        for (int j = 0; j < 8; ++j) {
          float p;
          asm("v_exp_f32 %0, %1" : "=v"(p) : "v"(s_prev[half*8 + j]));
          pe[j] = p;
          Lp += p;
        }
        uint32_t a0, a1, a2, a3;
        asm("v_cvt_pk_bf16_f32 %0, %1, %2" : "=v"(a0) : "v"(pe[0]), "v"(pe[1]));
        asm("v_cvt_pk_bf16_f32 %0, %1, %2" : "=v"(a1) : "v"(pe[2]), "v"(pe[3]));
        asm("v_cvt_pk_bf16_f32 %0, %1, %2" : "=v"(a2) : "v"(pe[4]), "v"(pe[5]));
        asm("v_cvt_pk_bf16_f32 %0, %1, %2" : "=v"(a3) : "v"(pe[6]), "v"(pe[7]));
        asm("v_permlane32_swap_b32 %0, %1" : "+v"(a0), "+v"(a2));
        asm("v_permlane32_swap_b32 %0, %1" : "+v"(a1), "+v"(a3));
        union { uint32_t wd[4]; s16x8 v; } u;
        u.wd[0] = a0; u.wd[1] = a1; u.wd[2] = a2; u.wd[3] = a3;
        pf[half] = u.v;
      }
    }
    __builtin_amdgcn_s_setprio(0);
    __builtin_amdgcn_s_barrier();      // narrowed: gates only kl[cur] reads
    asm volatile("" ::: "memory");
    if (it < 30) stageK(cur, mbase + (it + 2)*32);   // -> kl[it&1]

    // PV(it-1): after barrier2 — overlaps stageK flight, de-convoys from S
    if (it > 0) {
      const char* vc = vl + vsR*16384;
      __builtin_amdgcn_s_setprio(1);
#pragma unroll
      for (int ks = 0; ks < 2; ++ks) {
#pragma unroll
        for (int ct = 0; ct < 8; ++ct) {
          s16x8 vf = *(const s16x8*)(vc + (ks*2 + h)*4096 + (ct*32 + cl)*16);
          oacc[ct] = __builtin_amdgcn_mfma_f32_32x32x16_bf16(vf, pf[ks], oacc[ct], 0, 0, 0);
        }
      }
      __builtin_amdgcn_s_setprio(0);
    }
    s_prev = s0;
  }

  // epilogue: softmax(31) + PV(31) on vl[31%3 = 1]
  asm volatile("s_waitcnt vmcnt(0)" ::: "memory");
  __builtin_amdgcn_s_barrier();
  asm volatile("" ::: "memory");
  {
#pragma unroll
    for (int half = 0; half < 2; ++half) {
      float pe[8];
#pragma unroll
      for (int j = 0; j < 8; ++j) {
        float p;
        asm("v_exp_f32 %0, %1" : "=v"(p) : "v"(s_prev[half*8 + j]));
        pe[j] = p;
        Lp += p;
      }
      uint32_t a0, a1, a2, a3;
      asm("v_cvt_pk_bf16_f32 %0, %1, %2" : "=v"(a0) : "v"(pe[0]), "v"(pe[1]));
      asm("v_cvt_pk_bf16_f32 %0, %1, %2" : "=v"(a1) : "v"(pe[2]), "v"(pe[3]));
      asm("v_cvt_pk_bf16_f32 %0, %1, %2" : "=v"(a2) : "v"(pe[4]), "v"(pe[5]));
      asm("v_cvt_pk_bf16_f32 %0, %1, %2" : "=v"(a3) : "v"(pe[6]), "v"(pe[7]));
      asm("v_permlane32_swap_b32 %0, %1" : "+v"(a0), "+v"(a2));
      asm("v_permlane32_swap_b32 %0, %1" : "+v"(a1), "+v"(a3));
      union { uint32_t wd[4]; s16x8 v; } u;
      u.wd[0] = a0; u.wd[1] = a1; u.wd[2] = a2; u.wd[3] = a3;
      pf[half] = u.v;
    }
    const char* vc = vl + ((31 % 3) * 16384);
    __builtin_amdgcn_s_setprio(1);
#pragma unroll
    for (int ks = 0; ks < 2; ++ks) {
#pragma unroll
      for (int ct = 0; ct < 8; ++ct) {
        s16x8 vf = *(const s16x8*)(vc + (ks*2 + h)*4096 + (ct*32 + cl)*16);
        oacc[ct] = __builtin_amdgcn_mfma_f32_32x32x16_bf16(vf, pf[ks], oacc[ct], 0, 0, 0);
      }
    }
    __builtin_amdgcn_s_setprio(0);
  }

  // epilogue: partial L and partial O^T (bf16 pairs along c)
  float Lq = Lp + __shfl_xor(Lp, 32, 64);
  const int pb = part*4 + b;
  if (lane < 32) Lpart[(size_t)pb*NN + q] = Lq;
  const size_t basePB = (size_t)pb * 128 * NN;
#pragma unroll
  for (int ct = 0; ct < 8; ++ct) {
#pragma unroll
    for (int i2 = 0; i2 < 8; ++i2) {
      const int i = i2*2;
      float lo_ = oacc[ct][i], hi_ = oacc[ct][i+1];
      uint32_t pk;
      asm("v_cvt_pk_bf16_f32 %0, %1, %2" : "=v"(pk) : "v"(lo_), "v"(hi_));
      const int cp = ct*16 + ((i&3)>>1) + 4*(i>>2) + 2*h;  // c/2
      Op32[basePB + (size_t)cp*NN + q] = pk;
    }
  }
}

// ======== fused merge(4 partials) + proj GEMM + bias + fp32 residual ========
__global__ __launch_bounds__(512) void proj_kernel(
    const uint32_t* __restrict__ Op32, const float* __restrict__ Lpart,
    const u16* __restrict__ wp, const float* __restrict__ bp,
    const float* __restrict__ resid, float* __restrict__ out) {
  __shared__ char t2[32768];  // [64 m][256 c] bf16, row-swizzled
  const int b = blockIdx.y, m0 = blockIdx.x * 64, t = threadIdx.x;
  {
    const int q = m0 + (t & 63);
    const int m = t & 63;
    const int cg = t >> 6;  // 0..7
    float L = 0.f;
#pragma unroll
    for (int p = 0; p < 4; ++p) L += Lpart[(size_t)(p*4 + b)*NN + q];
    const float inv = 1.0f / L;
#pragma unroll
    for (int i = 0; i < 16; ++i) {
      const int cp = cg*16 + i;
      float v0 = 0.f, v1 = 0.f;
#pragma unroll
      for (int p = 0; p < 4; ++p) {
        uint32_t pk = Op32[(size_t)(p*4 + b)*128*NN + (size_t)cp*NN + q];
        v0 += bf2f(pk & 0xffffu);
        v1 += bf2f(pk >> 16);
      }
      v0 *= inv; v1 *= inv;
      uint32_t opk;
      asm("v_cvt_pk_bf16_f32 %0, %1, %2" : "=v"(opk) : "v"(v0), "v"(v1));
      *(uint32_t*)(t2 + m*512 + ((cp*4) ^ ((m & 7) << 4))) = opk;
    }
  }
  __syncthreads();
  const int lane = t & 63, w = t >> 6;
  const int wm = w >> 2, wo = w & 3;
  const int hi = lane >> 4, lo = lane & 15;
  f32x4 acc[2][4] = {};
  for (int kc = 0; kc < 8; ++kc) {
    s16x8 xf[2];
#pragma unroll
    for (int mf = 0; mf < 2; ++mf) {
      int m = wm*32 + mf*16 + lo;
      xf[mf] = *(const s16x8*)(t2 + m*512 + ((kc*64 + hi*16) ^ ((m & 7) << 4)));
    }
#pragma unroll
    for (int of = 0; of < 4; ++of) {
      int o = wo*64 + of*16 + lo;
      s16x8 wf = *(const s16x8*)(wp + (size_t)o*256 + kc*32 + hi*8);
      acc[0][of] = __builtin_amdgcn_mfma_f32_16x16x32_bf16(wf, xf[0], acc[0][of], 0, 0, 0);
      acc[1][of] = __builtin_amdgcn_mfma_f32_16x16x32_bf16(wf, xf[1], acc[1][of], 0, 0, 0);
    }
  }
#pragma unroll
  for (int mf = 0; mf < 2; ++mf)
#pragma unroll
    for (int of = 0; of < 4; ++of) {
      int oc0 = wo*64 + of*16 + hi*4;
#pragma unroll
      for (int r = 0; r < 4; ++r) {
        int m = m0 + wm*32 + mf*16 + lo;
        size_t idx = ((size_t)b*CC + oc0 + r)*NN + m;
        out[idx] = acc[mf][of][r] + bp[oc0 + r] + resid[idx];
      }
    }
}

extern "C" void kernel_launch(void* const* d_in, const int* in_sizes, int n_in,
                              void* d_out, int out_size, void* d_ws, size_t ws_size,
                              hipStream_t stream) {
  const float* x  = (const float*)d_in[0];
  const float* gg = (const float*)d_in[1];
  const float* gb = (const float*)d_in[2];
  const float* wq = (const float*)d_in[3];
  const float* bq = (const float*)d_in[4];
  const float* wk = (const float*)d_in[5];
  const float* bk = (const float*)d_in[6];
  const float* wv = (const float*)d_in[7];
  const float* bv = (const float*)d_in[8];
  const float* wp = (const float*)d_in[9];
  const float* bp = (const float*)d_in[10];
  float* out = (float*)d_out;

  char* ws = (char*)d_ws;
  const size_t MATS = (size_t)BB * NN * CC;
  u16* wbf  = (u16*)ws;                 // 512 KB (Q,K,V,P bf16 weights)
  u16* Qtm  = (u16*)(ws + (512 << 10)); // 8 MB token-major
  u16* Ktm  = Qtm + MATS;               // 8 MB token-major
  u16* Vcm  = Ktm + MATS;               // 8 MB channel-major
  uint32_t* Op32 = (uint32_t*)(Vcm + MATS);            // 33.5 MB partials
  float* Lpart   = (float*)(Op32 + (size_t)16*128*NN); // 256 KB
  float* part    = Lpart + (size_t)16*NN;              // 1024 floats

  prep_kernel<<<768, 256, 0, stream>>>(wq, wk, wv, wp, wbf, x, part);
  gnqkv_kernel<<<dim3(64, 4), 512, 0, stream>>>(x, part, gg, gb, wbf,
                                                bq, bk, bv, Qtm, Ktm, Vcm);
  hipFuncSetAttribute((const void*)flash_kernel,
                      hipFuncAttributeMaxDynamicSharedMemorySize, 81920);
  flash_kernel<<<512, 256, 81920, stream>>>(Qtm, Ktm, Vcm, Op32, Lpart);
  proj_kernel<<<dim3(64, 4), 512, 0, stream>>>(Op32, Lpart, wbf + 3*65536,
                                               bp, x, out);
}

// Round 13
// 139.888 us; speedup vs baseline: 1.0537x; 1.0537x over previous
//
#include <hip/hip_runtime.h>
#include <stdint.h>

#define BB 4
#define CC 256
#define NN 4096
#define GG 8

typedef unsigned short u16;
typedef __attribute__((ext_vector_type(4))) float f32x4;
typedef __attribute__((ext_vector_type(16))) float f32x16;
typedef __attribute__((ext_vector_type(8))) short s16x8;
typedef __attribute__((ext_vector_type(4))) u16 u16x4;
typedef __attribute__((ext_vector_type(8))) u16 u16x8;

#define QSCALE 0.0901684857f  /* log2(e)/16 folded into wq/bq */

__device__ __forceinline__ u16 f2bf(float f) {
  union { float f; uint32_t u; } v; v.f = f;
  return (u16)((v.u + 0x7FFFu + ((v.u >> 16) & 1u)) >> 16);
}
__device__ __forceinline__ float bf2f(uint32_t u) {
  union { uint32_t u; float f; } v; v.u = u << 16;
  return v.f;
}

__device__ __forceinline__ void async16(const void* g, void* l) {
  __builtin_amdgcn_global_load_lds(
      (const __attribute__((address_space(1))) void*)g,
      (__attribute__((address_space(3))) void*)l, 16, 0, 0);
}

// ======== fused weight-cvt (256 blocks) + GN partial sums (512 blocks) ========
__global__ __launch_bounds__(256) void prep_kernel(
    const float* __restrict__ wq, const float* __restrict__ wk,
    const float* __restrict__ wv, const float* __restrict__ wp,
    u16* __restrict__ dst, const float* __restrict__ x,
    float* __restrict__ part) {
  const int bid = blockIdx.x;
  if (bid < 256) {
    const int mat = bid >> 6;
    const float* src = (mat == 0) ? wq : (mat == 1) ? wk : (mat == 2) ? wv : wp;
    const float sc = (mat == 0) ? QSCALE : 1.0f;
    int i = (bid & 63) * 256 + threadIdx.x;
    f32x4 v = ((const f32x4*)src)[i];
    u16x4 o;
    o[0] = f2bf(v[0]*sc); o[1] = f2bf(v[1]*sc);
    o[2] = f2bf(v[2]*sc); o[3] = f2bf(v[3]*sc);
    ((u16x4*)(dst + (size_t)mat * 65536))[i] = o;
    return;
  }
  const int id = bid - 256;
  const int bg = id >> 4, seg = id & 15;  // 32 x 16
  const f32x4* xp = (const f32x4*)(x + (size_t)bg * 131072 + seg * 8192);
  float s = 0.f, ss = 0.f;
  for (int i = threadIdx.x; i < 2048; i += 256) {
    f32x4 v = xp[i];
    s += v[0] + v[1] + v[2] + v[3];
    ss += v[0]*v[0] + v[1]*v[1] + v[2]*v[2] + v[3]*v[3];
  }
  for (int d = 1; d < 64; d <<= 1) {
    s += __shfl_xor(s, d, 64);
    ss += __shfl_xor(ss, d, 64);
  }
  __shared__ float red[8];
  int w = threadIdx.x >> 6, lane = threadIdx.x & 63;
  if (lane == 0) { red[w*2] = s; red[w*2+1] = ss; }
  __syncthreads();
  if (threadIdx.x == 0) {
    part[(bg*16 + seg)*2]     = red[0]+red[2]+red[4]+red[6];
    part[(bg*16 + seg)*2 + 1] = red[1]+red[3]+red[5]+red[7];
  }
}

// ======== fused GN-apply + QKV GEMM (single pass over kc for Q,K,V) ========
__global__ __launch_bounds__(512) void gnqkv_kernel(
    const float* __restrict__ x, const float* __restrict__ part,
    const float* __restrict__ gamma, const float* __restrict__ beta,
    const u16* __restrict__ wbf,
    const float* __restrict__ bq, const float* __restrict__ bk,
    const float* __restrict__ bv,
    u16* __restrict__ Qtm, u16* __restrict__ Ktm, u16* __restrict__ Vcm) {
  __shared__ float gstat[16];
  __shared__ char t1[32768];  // [256 c][64 n] bf16, XOR-swizzled
  __shared__ char t2[32768];  // [64 n][256 c] bf16, row-swizzled for B-frags
  const int b = blockIdx.y, n0 = blockIdx.x * 64, t = threadIdx.x;
  if (t < 8) {
    float S = 0.f, SS = 0.f;
    for (int seg = 0; seg < 16; ++seg) {
      S  += part[((b*8 + t)*16 + seg)*2];
      SS += part[((b*8 + t)*16 + seg)*2 + 1];
    }
    float mean = S * (1.0f/131072.0f);
    float var = SS * (1.0f/131072.0f) - mean*mean;
    gstat[t*2] = mean;
    gstat[t*2+1] = rsqrtf(var + 1e-5f);
  }
  __syncthreads();
  for (int p = 0; p < 8; ++p) {
    int c = p*32 + (t >> 4);
    int n4 = (t & 15) * 4;
    f32x4 v = *(const f32x4*)(x + ((size_t)b*CC + c)*NN + n0 + n4);
    float mean = gstat[(c>>5)*2], rstd = gstat[(c>>5)*2+1];
    float ga = gamma[c] * rstd;
    float be = beta[c] - mean * ga;
    u16x4 o;
    o[0]=f2bf(v[0]*ga+be); o[1]=f2bf(v[1]*ga+be);
    o[2]=f2bf(v[2]*ga+be); o[3]=f2bf(v[3]*ga+be);
    int swz = (((c & 7) ^ ((c >> 3) & 7)) << 4);
    *(u16x4*)(t1 + c*128 + ((n4*2) ^ swz)) = o;
  }
  __syncthreads();
  for (int p = 0; p < 4; ++p) {
    int n = p*16 + (t >> 5);
    int c0 = (t & 31) * 8;
    u16x8 o;
#pragma unroll
    for (int j = 0; j < 8; ++j) {
      int c = c0 + j;
      int swz = (((c & 7) ^ ((c >> 3) & 7)) << 4);
      o[j] = *(const u16*)(t1 + c*128 + ((n*2) ^ swz));
    }
    *(u16x8*)(t2 + n*512 + ((c0*2) ^ ((n & 7) << 4))) = o;
  }
  __syncthreads();
  const int lane = t & 63, w = t >> 6;
  const int wn = w >> 2, wo = w & 3;
  const int hi = lane >> 4, lo = lane & 15;
  f32x4 accQ[2][4] = {}, accK[2][4] = {}, accV[2][4] = {};
  for (int kc = 0; kc < 8; ++kc) {
    s16x8 xf[2];
#pragma unroll
    for (int nf = 0; nf < 2; ++nf) {
      int n = wn*32 + nf*16 + lo;
      xf[nf] = *(const s16x8*)(t2 + n*512 + ((kc*64 + hi*16) ^ ((n & 7) << 4)));
    }
#pragma unroll
    for (int of = 0; of < 4; ++of) {
      int o = wo*64 + of*16 + lo;
      s16x8 wfq = *(const s16x8*)(wbf + 0*65536 + (size_t)o*256 + kc*32 + hi*8);
      s16x8 wfk = *(const s16x8*)(wbf + 1*65536 + (size_t)o*256 + kc*32 + hi*8);
      s16x8 wfv = *(const s16x8*)(wbf + 2*65536 + (size_t)o*256 + kc*32 + hi*8);
#pragma unroll
      for (int nf = 0; nf < 2; ++nf) {
        accQ[nf][of] = __builtin_amdgcn_mfma_f32_16x16x32_bf16(xf[nf], wfq, accQ[nf][of], 0, 0, 0);
        accK[nf][of] = __builtin_amdgcn_mfma_f32_16x16x32_bf16(xf[nf], wfk, accK[nf][of], 0, 0, 0);
        accV[nf][of] = __builtin_amdgcn_mfma_f32_16x16x32_bf16(wfv, xf[nf], accV[nf][of], 0, 0, 0);
      }
    }
  }
#pragma unroll
  for (int nf = 0; nf < 2; ++nf)
#pragma unroll
    for (int of = 0; of < 4; ++of) {
      int oc = wo*64 + of*16 + lo;
      float bvq = bq[oc] * QSCALE;
      float bvk = bk[oc];
#pragma unroll
      for (int r = 0; r < 4; ++r) {
        int n = n0 + wn*32 + nf*16 + hi*4 + r;
        Qtm[((size_t)b*NN + n)*CC + oc] = f2bf(accQ[nf][of][r] + bvq);
        Ktm[((size_t)b*NN + n)*CC + oc] = f2bf(accK[nf][of][r] + bvk);
      }
#pragma unroll
      for (int r = 0; r < 4; ++r) {
        int ocv = wo*64 + of*16 + hi*4 + r;
        int n = n0 + wn*32 + nf*16 + lo;
        Vcm[((size_t)b*CC + ocv)*NN + n] = f2bf(accV[nf][of][r] + bv[ocv]);
      }
    }
}

// ======== flash v11 (proven best): softmax-shift pipeline ========
// Window it: S(it) MFMA-chain ∥ softmax(it-1) VALU, then PV(it-1).
__global__ __launch_bounds__(256, 2) void flash_kernel(
    const u16* __restrict__ Q, const u16* __restrict__ K,
    const u16* __restrict__ V, uint32_t* __restrict__ Op32,
    float* __restrict__ Lpart) {
  __shared__ char kl[2][16384];  // [32 cslot][32 m][16B] per buffer
  __shared__ char vl[2][16384];  // [4 mslot][256 c][16B] per buffer
  const int bid = blockIdx.x;
  const int b    = bid & 3;
  const int part = ((bid >> 2) & 1) | (((bid >> 8) & 1) << 1);
  const int qb   = (bid >> 3) & 31;
  const int tid = threadIdx.x;
  const int lane = tid & 63;
  const int w = tid >> 6;
  const int cl = lane & 31;
  const int h = lane >> 5;
  const int q = qb*128 + w*32 + cl;

  s16x8 qreg[16];
  {
    const u16* qp = Q + ((size_t)b*NN + q)*CC + h*8;
#pragma unroll
    for (int kc = 0; kc < 16; ++kc) qreg[kc] = *(const s16x8*)(qp + kc*16);
  }
  f32x16 oacc[8];
#pragma unroll
  for (int i = 0; i < 8; ++i) oacc[i] = (f32x16)0.f;
  float Lp = 0.f;

  const char* kbase = (const char*)(K + (size_t)b*NN*CC);
  const char* vbase = (const char*)(V + (size_t)b*CC*NN);
  const int mbase = part*1024;

  auto stageK = [&](int buf, int m0) {
#pragma unroll
    for (int p = 0; p < 4; ++p)   // K: [cslot][m][16B]
      async16(kbase + (size_t)(m0 + (tid & 31))*512 + ((tid >> 5) + p*8)*16,
              kl[buf] + p*4096 + tid*16);
  };
  auto stageV = [&](int buf, int m0) {
#pragma unroll
    for (int p = 0; p < 4; ++p)   // V: [mslot][c][16B]
      async16(vbase + (size_t)tid*8192 + (size_t)m0*2 + p*16,
              vl[buf] + p*4096 + tid*16);
  };

  stageK(0, mbase);
  stageK(1, mbase + 32);
  stageV(0, mbase);

  f32x16 s_prev;                 // S(it-1), carried across the barrier
  s16x8 pf[2];                   // P(it-1) frags, built this window

  for (int it = 0; it < 32; ++it) {
    const int cur = it & 1;
    if (it == 31) asm volatile("s_waitcnt vmcnt(4)" ::: "memory");
    else          asm volatile("s_waitcnt vmcnt(8)" ::: "memory");
    __builtin_amdgcn_s_barrier();
    asm volatile("" ::: "memory");  // LDS reads stay below barrier

    // S(it): single dependent MFMA chain — its latency covers softmax VALU below
    f32x16 s0 = (f32x16)0.f;
    __builtin_amdgcn_s_setprio(1);
#pragma unroll
    for (int kc = 0; kc < 16; ++kc) {
      s16x8 kf = *(const s16x8*)(kl[cur] + (kc*2 + h)*512 + cl*16);
      s0 = __builtin_amdgcn_mfma_f32_32x32x16_bf16(kf, qreg[kc], s0, 0, 0, 0);
    }

    if (it > 0) {
      // softmax(it-1): VALU/TRANS — co-issues under S(it)'s MFMA chain
#pragma unroll
      for (int half = 0; half < 2; ++half) {
        float pe[8];
#pragma unroll
        for (int j = 0; j < 8; ++j) {
          float p;
          asm("v_exp_f32 %0, %1" : "=v"(p) : "v"(s_prev[half*8 + j]));
          pe[j] = p;
          Lp += p;
        }
        uint32_t a0, a1, a2, a3;
        asm("v_cvt_pk_bf16_f32 %0, %1, %2" : "=v"(a0) : "v"(pe[0]), "v"(pe[1]));
        asm("v_cvt_pk_bf16_f32 %0, %1, %2" : "=v"(a1) : "v"(pe[2]), "v"(pe[3]));
        asm("v_cvt_pk_bf16_f32 %0, %1, %2" : "=v"(a2) : "v"(pe[4]), "v"(pe[5]));
        asm("v_cvt_pk_bf16_f32 %0, %1, %2" : "=v"(a3) : "v"(pe[6]), "v"(pe[7]));
        asm("v_permlane32_swap_b32 %0, %1" : "+v"(a0), "+v"(a2));
        asm("v_permlane32_swap_b32 %0, %1" : "+v"(a1), "+v"(a3));
        union { uint32_t wd[4]; s16x8 v; } u;
        u.wd[0] = a0; u.wd[1] = a1; u.wd[2] = a2; u.wd[3] = a3;
        pf[half] = u.v;
      }
      // PV(it-1): O^T += V^T . P^T  (V(it-1) in vl[(it-1)&1] = vl[cur^1])
      const char* vc = vl[cur ^ 1];
#pragma unroll
      for (int ks = 0; ks < 2; ++ks) {
#pragma unroll
        for (int ct = 0; ct < 8; ++ct) {
          s16x8 vf = *(const s16x8*)(vc + (ks*2 + h)*4096 + (ct*32 + cl)*16);
          oacc[ct] = __builtin_amdgcn_mfma_f32_32x32x16_bf16(vf, pf[ks], oacc[ct], 0, 0, 0);
        }
      }
    }
    __builtin_amdgcn_s_setprio(0);
    s_prev = s0;
    __builtin_amdgcn_s_barrier();   // all LDS reads of kl[cur], vl[cur^1] done
    asm volatile("" ::: "memory");
    if (it < 30) stageK(cur, mbase + (it + 2)*32);         // -> kl[it&1]
    if (it < 31) stageV(cur ^ 1, mbase + (it + 1)*32);     // -> vl[(it+1)&1]
  }

  // epilogue: softmax(31) + PV(31) on vl[1]
  asm volatile("s_waitcnt vmcnt(0)" ::: "memory");
  __builtin_amdgcn_s_barrier();
  asm volatile("" ::: "memory");
  {
#pragma unroll
    for (int half = 0; half < 2; ++half) {
      float pe[8];
#pragma unroll
      for (int j = 0; j < 8; ++j) {
        float p;
        asm("v_exp_f32 %0, %1" : "=v"(p) : "v"(s_prev[half*8 + j]));
        pe[j] = p;
        Lp += p;
      }
      uint32_t a0, a1, a2, a3;
      asm("v_cvt_pk_bf16_f32 %0, %1, %2" : "=v"(a0) : "v"(pe[0]), "v"(pe[1]));
      asm("v_cvt_pk_bf16_f32 %0, %1, %2" : "=v"(a1) : "v"(pe[2]), "v"(pe[3]));
      asm("v_cvt_pk_bf16_f32 %0, %1, %2" : "=v"(a2) : "v"(pe[4]), "v"(pe[5]));
      asm("v_cvt_pk_bf16_f32 %0, %1, %2" : "=v"(a3) : "v"(pe[6]), "v"(pe[7]));
      asm("v_permlane32_swap_b32 %0, %1" : "+v"(a0), "+v"(a2));
      asm("v_permlane32_swap_b32 %0, %1" : "+v"(a1), "+v"(a3));
      union { uint32_t wd[4]; s16x8 v; } u;
      u.wd[0] = a0; u.wd[1] = a1; u.wd[2] = a2; u.wd[3] = a3;
      pf[half] = u.v;
    }
    const char* vc = vl[1];
    __builtin_amdgcn_s_setprio(1);
#pragma unroll
    for (int ks = 0; ks < 2; ++ks) {
#pragma unroll
      for (int ct = 0; ct < 8; ++ct) {
        s16x8 vf = *(const s16x8*)(vc + (ks*2 + h)*4096 + (ct*32 + cl)*16);
        oacc[ct] = __builtin_amdgcn_mfma_f32_32x32x16_bf16(vf, pf[ks], oacc[ct], 0, 0, 0);
      }
    }
    __builtin_amdgcn_s_setprio(0);
  }

  // epilogue: partial L and partial O^T (bf16 pairs along c)
  float Lq = Lp + __shfl_xor(Lp, 32, 64);
  const int pb = part*4 + b;
  if (lane < 32) Lpart[(size_t)pb*NN + q] = Lq;
  const size_t basePB = (size_t)pb * 128 * NN;
#pragma unroll
  for (int ct = 0; ct < 8; ++ct) {
#pragma unroll
    for (int i2 = 0; i2 < 8; ++i2) {
      const int i = i2*2;
      float lo_ = oacc[ct][i], hi_ = oacc[ct][i+1];
      uint32_t pk;
      asm("v_cvt_pk_bf16_f32 %0, %1, %2" : "=v"(pk) : "v"(lo_), "v"(hi_));
      const int cp = ct*16 + ((i&3)>>1) + 4*(i>>2) + 2*h;  // c/2
      Op32[basePB + (size_t)cp*NN + q] = pk;
    }
  }
}

// ======== fused merge(4 partials) + proj GEMM + bias + fp32 residual ========
__global__ __launch_bounds__(512) void proj_kernel(
    const uint32_t* __restrict__ Op32, const float* __restrict__ Lpart,
    const u16* __restrict__ wp, const float* __restrict__ bp,
    const float* __restrict__ resid, float* __restrict__ out) {
  __shared__ char t2[32768];  // [64 m][256 c] bf16, row-swizzled
  const int b = blockIdx.y, m0 = blockIdx.x * 64, t = threadIdx.x;
  {
    const int q = m0 + (t & 63);
    const int m = t & 63;
    const int cg = t >> 6;  // 0..7
    float L = 0.f;
#pragma unroll
    for (int p = 0; p < 4; ++p) L += Lpart[(size_t)(p*4 + b)*NN + q];
    const float inv = 1.0f / L;
#pragma unroll
    for (int i = 0; i < 16; ++i) {
      const int cp = cg*16 + i;
      float v0 = 0.f, v1 = 0.f;
#pragma unroll
      for (int p = 0; p < 4; ++p) {
        uint32_t pk = Op32[(size_t)(p*4 + b)*128*NN + (size_t)cp*NN + q];
        v0 += bf2f(pk & 0xffffu);
        v1 += bf2f(pk >> 16);
      }
      v0 *= inv; v1 *= inv;
      uint32_t opk;
      asm("v_cvt_pk_bf16_f32 %0, %1, %2" : "=v"(opk) : "v"(v0), "v"(v1));
      *(uint32_t*)(t2 + m*512 + ((cp*4) ^ ((m & 7) << 4))) = opk;
    }
  }
  __syncthreads();
  const int lane = t & 63, w = t >> 6;
  const int wm = w >> 2, wo = w & 3;
  const int hi = lane >> 4, lo = lane & 15;
  f32x4 acc[2][4] = {};
  for (int kc = 0; kc < 8; ++kc) {
    s16x8 xf[2];
#pragma unroll
    for (int mf = 0; mf < 2; ++mf) {
      int m = wm*32 + mf*16 + lo;
      xf[mf] = *(const s16x8*)(t2 + m*512 + ((kc*64 + hi*16) ^ ((m & 7) << 4)));
    }
#pragma unroll
    for (int of = 0; of < 4; ++of) {
      int o = wo*64 + of*16 + lo;
      s16x8 wf = *(const s16x8*)(wp + (size_t)o*256 + kc*32 + hi*8);
      acc[0][of] = __builtin_amdgcn_mfma_f32_16x16x32_bf16(wf, xf[0], acc[0][of], 0, 0, 0);
      acc[1][of] = __builtin_amdgcn_mfma_f32_16x16x32_bf16(wf, xf[1], acc[1][of], 0, 0, 0);
    }
  }
#pragma unroll
  for (int mf = 0; mf < 2; ++mf)
#pragma unroll
    for (int of = 0; of < 4; ++of) {
      int oc0 = wo*64 + of*16 + hi*4;
#pragma unroll
      for (int r = 0; r < 4; ++r) {
        int m = m0 + wm*32 + mf*16 + lo;
        size_t idx = ((size_t)b*CC + oc0 + r)*NN + m;
        out[idx] = acc[mf][of][r] + bp[oc0 + r] + resid[idx];
      }
    }
}

extern "C" void kernel_launch(void* const* d_in, const int* in_sizes, int n_in,
                              void* d_out, int out_size, void* d_ws, size_t ws_size,
                              hipStream_t stream) {
  const float* x  = (const float*)d_in[0];
  const float* gg = (const float*)d_in[1];
  const float* gb = (const float*)d_in[2];
  const float* wq = (const float*)d_in[3];
  const float* bq = (const float*)d_in[4];
  const float* wk = (const float*)d_in[5];
  const float* bk = (const float*)d_in[6];
  const float* wv = (const float*)d_in[7];
  const float* bv = (const float*)d_in[8];
  const float* wp = (const float*)d_in[9];
  const float* bp = (const float*)d_in[10];
  float* out = (float*)d_out;

  char* ws = (char*)d_ws;
  const size_t MATS = (size_t)BB * NN * CC;
  u16* wbf  = (u16*)ws;                 // 512 KB (Q,K,V,P bf16 weights)
  u16* Qtm  = (u16*)(ws + (512 << 10)); // 8 MB token-major
  u16* Ktm  = Qtm + MATS;               // 8 MB token-major
  u16* Vcm  = Ktm + MATS;               // 8 MB channel-major
  uint32_t* Op32 = (uint32_t*)(Vcm + MATS);            // 33.5 MB partials
  float* Lpart   = (float*)(Op32 + (size_t)16*128*NN); // 256 KB
  float* part    = Lpart + (size_t)16*NN;              // 1024 floats

  prep_kernel<<<768, 256, 0, stream>>>(wq, wk, wv, wp, wbf, x, part);
  gnqkv_kernel<<<dim3(64, 4), 512, 0, stream>>>(x, part, gg, gb, wbf,
                                                bq, bk, bv, Qtm, Ktm, Vcm);
  flash_kernel<<<512, 256, 0, stream>>>(Qtm, Ktm, Vcm, Op32, Lpart);
  proj_kernel<<<dim3(64, 4), 512, 0, stream>>>(Op32, Lpart, wbf + 3*65536,
                                               bp, x, out);
}